// Round 2
// 289.374 us; speedup vs baseline: 1.3634x; 1.3634x over previous
//
#include <hip/hip_runtime.h>
#include <hip/hip_bf16.h>

// Problem constants (reference: B=2, N=2048, DIM=1024, INTER=1024, HEAD=16, N_SEG=4)
#define BB 2
#define NN 2048
#define DIM 1024
#define INTER 1024
#define NHEAD 16
#define HDIM 64          // INTER / NHEAD
#define NSEG 4
#define QKVW (3 * INTER) // 3072

typedef __attribute__((ext_vector_type(8))) short bf16x8;
typedef __attribute__((ext_vector_type(4))) float f32x4;

static __device__ __forceinline__ unsigned short f2bf(float f) {
    __hip_bfloat16 h = __float2bfloat16(f);   // RNE
    return *reinterpret_cast<unsigned short*>(&h);
}
static __device__ __forceinline__ float bf2f(unsigned short u) {
    unsigned int x = ((unsigned int)u) << 16;
    return __builtin_bit_cast(float, x);
}
// Verified manual RNE (round-0 bit sequence), packs two f32 -> 2xbf16 in a dword.
static __device__ __forceinline__ unsigned int pack_bf16_rne(float lo, float hi) {
    unsigned int u = __builtin_bit_cast(unsigned int, lo);
    unsigned int v = __builtin_bit_cast(unsigned int, hi);
    u += 0x7FFFu + ((u >> 16) & 1u);
    v += 0x7FFFu + ((v >> 16) & 1u);
    return (u >> 16) | (v & 0xFFFF0000u);
}

// ---------------------------------------------------------------------------
// Prepass: fp32 -> bf16 elementwise (features). n must be /1024.
// ---------------------------------------------------------------------------
__global__ __launch_bounds__(256) void conv_f32_bf16(const float* __restrict__ in,
                                                     unsigned short* __restrict__ out) {
    int i = (blockIdx.x * 256 + threadIdx.x) * 4;
    float4 v = *(const float4*)&in[i];
    ushort4 o = {f2bf(v.x), f2bf(v.y), f2bf(v.z), f2bf(v.w)};
    *(ushort4*)&out[i] = o;
}

// ---------------------------------------------------------------------------
// Prepass: convert + transpose  in[R][C] fp32  ->  out[C][R] bf16.
// ---------------------------------------------------------------------------
__global__ __launch_bounds__(256) void transp_f32_bf16(const float* __restrict__ in,
                                                       unsigned short* __restrict__ out,
                                                       int R, int C) {
    __shared__ float tile[64][65];
    const int r0 = blockIdx.y * 64, c0 = blockIdx.x * 64;
    const int t = threadIdx.x;
#pragma unroll
    for (int it = 0; it < 4; ++it) {
        int r = it * 16 + (t >> 4);
        int c = (t & 15) * 4;
        float4 v = *(const float4*)&in[(size_t)(r0 + r) * C + c0 + c];
        tile[r][c] = v.x; tile[r][c + 1] = v.y; tile[r][c + 2] = v.z; tile[r][c + 3] = v.w;
    }
    __syncthreads();
#pragma unroll
    for (int it = 0; it < 4; ++it) {
        int c = it * 16 + (t >> 4);
        int r = (t & 15) * 4;
        ushort4 o = {f2bf(tile[r][c]), f2bf(tile[r + 1][c]), f2bf(tile[r + 2][c]), f2bf(tile[r + 3][c])};
        *(ushort4*)&out[(size_t)(c0 + c) * R + r0 + r] = o;
    }
}

// ---------------------------------------------------------------------------
// Prepass: convert + transpose + hi/lo split  in[R][C] fp32 -> oh/ol [C][R] bf16.
// oh = bf16(v), ol = bf16(v - oh)  (split-bf16 for near-fp32-exact MFMA GEMM).
// ---------------------------------------------------------------------------
__global__ __launch_bounds__(256) void transp_split_f32_bf16(const float* __restrict__ in,
                                                             unsigned short* __restrict__ oh,
                                                             unsigned short* __restrict__ ol,
                                                             int R, int C) {
    __shared__ float tile[64][65];
    const int r0 = blockIdx.y * 64, c0 = blockIdx.x * 64;
    const int t = threadIdx.x;
#pragma unroll
    for (int it = 0; it < 4; ++it) {
        int r = it * 16 + (t >> 4);
        int c = (t & 15) * 4;
        float4 v = *(const float4*)&in[(size_t)(r0 + r) * C + c0 + c];
        tile[r][c] = v.x; tile[r][c + 1] = v.y; tile[r][c + 2] = v.z; tile[r][c + 3] = v.w;
    }
    __syncthreads();
#pragma unroll
    for (int it = 0; it < 4; ++it) {
        int c = it * 16 + (t >> 4);
        int r = (t & 15) * 4;
        float v0 = tile[r][c], v1 = tile[r + 1][c], v2 = tile[r + 2][c], v3 = tile[r + 3][c];
        ushort4 hh, ll;
        hh.x = f2bf(v0); ll.x = f2bf(v0 - bf2f(hh.x));
        hh.y = f2bf(v1); ll.y = f2bf(v1 - bf2f(hh.y));
        hh.z = f2bf(v2); ll.z = f2bf(v2 - bf2f(hh.z));
        hh.w = f2bf(v3); ll.w = f2bf(v3 - bf2f(hh.w));
        *(ushort4*)&oh[(size_t)(c0 + c) * R + r0 + r] = hh;
        *(ushort4*)&ol[(size_t)(c0 + c) * R + r0 + r] = ll;
    }
}

// ---------------------------------------------------------------------------
// QKV GEMM, bf16 MFMA (m97 structure): [4096][1024] @ [3072][1024]^T.
// q|k columns (col<2048) -> Cqk [4096][2048]; v columns -> Vtg transposed
// [b][h*64+d][n] so attention can stage V with coalesced b128 loads.
// ---------------------------------------------------------------------------
#define GBK 32

__global__ __launch_bounds__(256) void gemm_qkv_mfma(
        const unsigned short* __restrict__ A,    // [4096][1024] bf16
        const unsigned short* __restrict__ Bt,   // [3072][1024] bf16
        unsigned short* __restrict__ Cqk,        // [4096][2048] bf16 (q|k)
        unsigned short* __restrict__ Vtg) {      // [2][1024][2048] bf16
    const int K = 1024;
    __shared__ __align__(16) unsigned short As[128][GBK];
    __shared__ __align__(16) unsigned short Bs[128][GBK];
    const int t = threadIdx.x;
    const int w = t >> 6, lane = t & 63, l15 = lane & 15, quad = lane >> 4;
    const int wr = w >> 1, wc = w & 1;
    const int row0 = blockIdx.y * 128, col0 = blockIdx.x * 128;
    const int lrow = lane >> 2;
    const int lkof = (lane & 3) * 8;

    f32x4 acc[4][4];
#pragma unroll
    for (int i = 0; i < 4; ++i)
#pragma unroll
        for (int j = 0; j < 4; ++j) acc[i][j] = (f32x4){0.f, 0.f, 0.f, 0.f};

    for (int k0 = 0; k0 < K; k0 += GBK) {
#pragma unroll
        for (int c = 0; c < 2; ++c) {
            int rbase = w * 32 + c * 16;
            const unsigned short* ga = A  + (size_t)(row0 + rbase + lrow) * K + k0 + lkof;
            const unsigned short* gb = Bt + (size_t)(col0 + rbase + lrow) * K + k0 + lkof;
            __builtin_amdgcn_global_load_lds(
                (const __attribute__((address_space(1))) void*)ga,
                (__attribute__((address_space(3))) void*)&As[rbase][0], 16, 0, 0);
            __builtin_amdgcn_global_load_lds(
                (const __attribute__((address_space(1))) void*)gb,
                (__attribute__((address_space(3))) void*)&Bs[rbase][0], 16, 0, 0);
        }
        __syncthreads();
        bf16x8 af[4], bfr[4];
#pragma unroll
        for (int i = 0; i < 4; ++i) af[i]  = *(const bf16x8*)&As[wr * 64 + i * 16 + l15][quad * 8];
#pragma unroll
        for (int j = 0; j < 4; ++j) bfr[j] = *(const bf16x8*)&Bs[wc * 64 + j * 16 + l15][quad * 8];
#pragma unroll
        for (int i = 0; i < 4; ++i)
#pragma unroll
            for (int j = 0; j < 4; ++j)
                acc[i][j] = __builtin_amdgcn_mfma_f32_16x16x32_bf16(af[i], bfr[j], acc[i][j], 0, 0, 0);
        __syncthreads();
    }

    if (col0 < 2048) {
#pragma unroll
        for (int i = 0; i < 4; ++i)
#pragma unroll
            for (int j = 0; j < 4; ++j)
#pragma unroll
                for (int r = 0; r < 4; ++r) {
                    int row = row0 + wr * 64 + i * 16 + quad * 4 + r;
                    int col = col0 + wc * 64 + j * 16 + l15;
                    Cqk[(size_t)row * 2048 + col] = f2bf(acc[i][j][r]);
                }
    } else {
#pragma unroll
        for (int i = 0; i < 4; ++i)
#pragma unroll
            for (int j = 0; j < 4; ++j) {
                int col = col0 + wc * 64 + j * 16 + l15 - 2048;   // h*64+d
                int row = row0 + wr * 64 + i * 16 + quad * 4;     // b*2048+n
                int bb = row >> 11, n = row & 2047;
                ushort4 o = {f2bf(acc[i][j][0]), f2bf(acc[i][j][1]),
                             f2bf(acc[i][j][2]), f2bf(acc[i][j][3])};
                *(ushort4*)&Vtg[((size_t)bb * INTER + col) * NN + n] = o;
            }
    }
}

// ---------------------------------------------------------------------------
// Out-projection: split-bf16 3-term MFMA GEMM (AhBh + AlBh + AhBl, AlBl ~2^-18
// dropped). Near-fp32 accuracy at bf16 MFMA rate. 128x64 tile -> 512 blocks.
// ---------------------------------------------------------------------------
__global__ __launch_bounds__(256) void gemm_out_split(
        const unsigned short* __restrict__ Ah,   // ctx hi  [4096][1024] bf16
        const unsigned short* __restrict__ Al,   // ctx lo  [4096][1024] bf16
        const unsigned short* __restrict__ Bh,   // W_out^T hi [1024][1024] bf16
        const unsigned short* __restrict__ Bl,   // W_out^T lo [1024][1024] bf16
        float* __restrict__ C) {                 // [4096][1024] fp32
    const int K = INTER, N = DIM;
    __shared__ __align__(16) unsigned short Ash[128][32];
    __shared__ __align__(16) unsigned short Asl[128][32];
    __shared__ __align__(16) unsigned short Bsh[64][32];
    __shared__ __align__(16) unsigned short Bsl[64][32];
    const int t = threadIdx.x;
    const int w = t >> 6, lane = t & 63, l15 = lane & 15, quad = lane >> 4;
    const int wr = w >> 1, wc = w & 1;           // 2x2 waves over 128x64
    const int row0 = blockIdx.y * 128, col0 = blockIdx.x * 64;
    const int lrow = lane >> 2, lkof = (lane & 3) * 8;

    f32x4 acc[4][2];
#pragma unroll
    for (int i = 0; i < 4; ++i)
#pragma unroll
        for (int j = 0; j < 2; ++j) acc[i][j] = (f32x4){0.f, 0.f, 0.f, 0.f};

    for (int k0 = 0; k0 < K; k0 += 32) {
#pragma unroll
        for (int c = 0; c < 2; ++c) {
            int rbase = w * 32 + c * 16;
            const unsigned short* gah = Ah + (size_t)(row0 + rbase + lrow) * K + k0 + lkof;
            const unsigned short* gal = Al + (size_t)(row0 + rbase + lrow) * K + k0 + lkof;
            __builtin_amdgcn_global_load_lds(
                (const __attribute__((address_space(1))) void*)gah,
                (__attribute__((address_space(3))) void*)&Ash[rbase][0], 16, 0, 0);
            __builtin_amdgcn_global_load_lds(
                (const __attribute__((address_space(1))) void*)gal,
                (__attribute__((address_space(3))) void*)&Asl[rbase][0], 16, 0, 0);
        }
        {
            int rbase = w * 16;
            const unsigned short* gbh = Bh + (size_t)(col0 + rbase + lrow) * K + k0 + lkof;
            const unsigned short* gbl = Bl + (size_t)(col0 + rbase + lrow) * K + k0 + lkof;
            __builtin_amdgcn_global_load_lds(
                (const __attribute__((address_space(1))) void*)gbh,
                (__attribute__((address_space(3))) void*)&Bsh[rbase][0], 16, 0, 0);
            __builtin_amdgcn_global_load_lds(
                (const __attribute__((address_space(1))) void*)gbl,
                (__attribute__((address_space(3))) void*)&Bsl[rbase][0], 16, 0, 0);
        }
        __syncthreads();
        bf16x8 ah[4], al[4], bh[2], bl[2];
#pragma unroll
        for (int i = 0; i < 4; ++i) {
            ah[i] = *(const bf16x8*)&Ash[wr * 64 + i * 16 + l15][quad * 8];
            al[i] = *(const bf16x8*)&Asl[wr * 64 + i * 16 + l15][quad * 8];
        }
#pragma unroll
        for (int j = 0; j < 2; ++j) {
            bh[j] = *(const bf16x8*)&Bsh[wc * 32 + j * 16 + l15][quad * 8];
            bl[j] = *(const bf16x8*)&Bsl[wc * 32 + j * 16 + l15][quad * 8];
        }
#pragma unroll
        for (int i = 0; i < 4; ++i)
#pragma unroll
            for (int j = 0; j < 2; ++j) {
                acc[i][j] = __builtin_amdgcn_mfma_f32_16x16x32_bf16(ah[i], bh[j], acc[i][j], 0, 0, 0);
                acc[i][j] = __builtin_amdgcn_mfma_f32_16x16x32_bf16(al[i], bh[j], acc[i][j], 0, 0, 0);
                acc[i][j] = __builtin_amdgcn_mfma_f32_16x16x32_bf16(ah[i], bl[j], acc[i][j], 0, 0, 0);
            }
        __syncthreads();
    }
#pragma unroll
    for (int i = 0; i < 4; ++i)
#pragma unroll
        for (int j = 0; j < 2; ++j)
#pragma unroll
            for (int r = 0; r < 4; ++r)
                C[(size_t)(row0 + wr * 64 + i * 16 + quad * 4 + r) * N +
                  col0 + wc * 32 + j * 16 + l15] = acc[i][j][r];
}

// ---------------------------------------------------------------------------
// Segment-masked attention, MFMA bf16, single sweep, DOUBLE-BUFFERED staging.
//  - QK^T swapped: mfma(K,Q) -> E^T, lane's 4 acc elems = consecutive j for
//    fixed i -> manual-RNE pack (verified bit sequence) + 2x ds_write_b64
//    replace 16x RNE + 16x ds_write_b16. El content identical to round 0.
//  - exp folded to exp2(s * (log2e/32)).
//  - segment masks via v_perm_b32 (bit-exact vs old cmp/cndmask chain).
//  - epilogue writes ctx as hi/lo bf16 pair for the split-bf16 out GEMM.
// ---------------------------------------------------------------------------
__global__ __launch_bounds__(256, 2) void attn_seg_mfma(
        const unsigned short* __restrict__ qk,    // bf16 [4096][2048] = q|k
        const unsigned short* __restrict__ vtg,   // bf16 [2][1024][2048]
        const int* __restrict__ mask,             // [B,N,N]
        unsigned short* __restrict__ ctxh,        // bf16 [4096][1024]
        unsigned short* __restrict__ ctxl) {      // bf16 [4096][1024]
    __shared__ __align__(16) unsigned short Ks[2][64][72];   // 18.4 KB
    __shared__ __align__(16) unsigned short Vt[2][64][72];   // 18.4 KB  [dim][key]
    __shared__ __align__(16) unsigned char  Mb[2][64][72];   //  9.2 KB
    __shared__ __align__(16) unsigned short El[4][16][72];   //  9.2 KB  per-wave E [i][j]

    const int t    = threadIdx.x;
    const int w    = t >> 6;
    const int lane = t & 63;
    const int l15  = lane & 15;
    const int quad = lane >> 4;
    const int i0   = blockIdx.x * 64;
    const int hh   = blockIdx.y;
    const int b    = blockIdx.z;

    bf16x8 qa0, qa1;
    {
        const unsigned short* qp =
            qk + (size_t)(b * NN + i0 + w * 16 + l15) * 2048 + hh * HDIM + quad * 8;
        qa0 = *(const bf16x8*)qp;
        qa1 = *(const bf16x8*)(qp + 32);
    }

    bf16x8 onesb;
    {
        short ob = (l15 == 0) ? (short)0x3F80 : (short)0;
#pragma unroll
        for (int j = 0; j < 8; ++j) onesb[j] = ob;
    }

    f32x4 acc[NSEG][5];
#pragma unroll
    for (int m = 0; m < NSEG; ++m)
#pragma unroll
        for (int nt = 0; nt < 5; ++nt) acc[m][nt] = (f32x4){0.f, 0.f, 0.f, 0.f};

    auto stage = [&](int bb, int j0) {
#pragma unroll
        for (int it = 0; it < 2; ++it) {
            int id = t + it * 256, key = id >> 3, dc = (id & 7) * 8;
            *(bf16x8*)&Ks[bb][key][dc] =
                *(const bf16x8*)&qk[(size_t)(b * NN + j0 + key) * 2048 + 1024 + hh * HDIM + dc];
        }
#pragma unroll
        for (int it = 0; it < 2; ++it) {
            int id = t + it * 256, d = id >> 3, c = (id & 7) * 8;
            *(bf16x8*)&Vt[bb][d][c] =
                *(const bf16x8*)&vtg[((size_t)b * INTER + hh * HDIM + d) * NN + j0 + c];
        }
#pragma unroll
        for (int it = 0; it < 4; ++it) {
            int id = t + it * 256, row = id >> 4, c4 = (id & 15) * 4;
            int4 mv = *(const int4*)&mask[(size_t)(b * NN + i0 + row) * NN + j0 + c4];
            unsigned int p = (unsigned)(mv.x & 3) | ((unsigned)(mv.y & 3) << 8) |
                             ((unsigned)(mv.z & 3) << 16) | ((unsigned)(mv.w & 3) << 24);
            *(unsigned int*)&Mb[bb][row][c4] = p;
        }
    };

    stage(0, 0);

    for (int jt = 0; jt < NN / 64; ++jt) {
        __syncthreads();                        // buf[jt&1] ready; buf[nxt] free
        if (jt + 1 < NN / 64) stage((jt + 1) & 1, (jt + 1) * 64);
        const int bb = jt & 1;

        // ---- E = exp(scale * Q K^T), swapped operands: D[j][i] ----
        // lane (quad,l15): rows j = nt*16+quad*4+r, col i = l15
#pragma unroll
        for (int nt = 0; nt < 4; ++nt) {
            f32x4 s = {0.f, 0.f, 0.f, 0.f};
            bf16x8 kb0 = *(const bf16x8*)&Ks[bb][nt * 16 + l15][quad * 8];
            bf16x8 kb1 = *(const bf16x8*)&Ks[bb][nt * 16 + l15][32 + quad * 8];
            s = __builtin_amdgcn_mfma_f32_16x16x32_bf16(kb0, qa0, s, 0, 0, 0);
            s = __builtin_amdgcn_mfma_f32_16x16x32_bf16(kb1, qa1, s, 0, 0, 0);
            // exp(x/32) = exp2(x * log2e/32); manual RNE pack (verified bits)
            float e0 = __builtin_amdgcn_exp2f(s[0] * 0.04508422f);
            float e1 = __builtin_amdgcn_exp2f(s[1] * 0.04508422f);
            float e2 = __builtin_amdgcn_exp2f(s[2] * 0.04508422f);
            float e3 = __builtin_amdgcn_exp2f(s[3] * 0.04508422f);
            uint2 pk;
            pk.x = pack_bf16_rne(e0, e1);
            pk.y = pack_bf16_rne(e2, e3);
            *(uint2*)&El[w][l15][nt * 16 + quad * 4] = pk;   // El[i][j..j+3], b64
        }

        // ---- PV: masked A variants x (4 dim tiles + ones tile) ----
#pragma unroll
        for (int ks = 0; ks < 2; ++ks) {
            union { int4 i; bf16x8 v; } ef;
            ef.i = *(const int4*)&El[w][l15][ks * 32 + quad * 8];
            uint2 sbv = *(const uint2*)&Mb[bb][w * 16 + l15][ks * 32 + quad * 8];
            // dup[d] = bytes [s(2d), s(2d), s(2d+1), s(2d+1)] (seg ids 0..3)
            unsigned int dup[4];
            dup[0] = __builtin_amdgcn_perm(0u, sbv.x, 0x01010000u);
            dup[1] = __builtin_amdgcn_perm(0u, sbv.x, 0x03030202u);
            dup[2] = __builtin_amdgcn_perm(0u, sbv.y, 0x01010000u);
            dup[3] = __builtin_amdgcn_perm(0u, sbv.y, 0x03030202u);
            const unsigned int* ed = (const unsigned int*)&ef.i;
            bf16x8 vb[4];
#pragma unroll
            for (int nt = 0; nt < 4; ++nt)
                vb[nt] = *(const bf16x8*)&Vt[bb][nt * 16 + l15][ks * 32 + quad * 8];
#pragma unroll
            for (int m = 0; m < NSEG; ++m) {
                const unsigned int Tm = 0xFFu << (8 * m);   // table: byte s -> (s==m)?0xFF:0
                union { int4 i; bf16x8 v; } wm;
#pragma unroll
                for (int d = 0; d < 4; ++d)
                    ((unsigned int*)&wm.i)[d] = ed[d] & __builtin_amdgcn_perm(0u, Tm, dup[d]);
#pragma unroll
                for (int nt = 0; nt < 4; ++nt)
                    acc[m][nt] = __builtin_amdgcn_mfma_f32_16x16x32_bf16(wm.v, vb[nt], acc[m][nt], 0, 0, 0);
                acc[m][4] = __builtin_amdgcn_mfma_f32_16x16x32_bf16(wm.v, onesb, acc[m][4], 0, 0, 0);
            }
        }
    }

    float rres[NSEG][4];
#pragma unroll
    for (int m = 0; m < NSEG; ++m)
#pragma unroll
        for (int r = 0; r < 4; ++r) {
            float sum = __shfl(acc[m][4][r], lane & 48, 64);
            rres[m][r] = (sum > 0.f) ? (1.f / sum) : 0.f;
        }
#pragma unroll
    for (int nt = 0; nt < 4; ++nt)
#pragma unroll
        for (int r = 0; r < 4; ++r) {
            float v = acc[0][nt][r] * rres[0][r] + acc[1][nt][r] * rres[1][r] +
                      acc[2][nt][r] * rres[2][r] + acc[3][nt][r] * rres[3][r];
            size_t idx = (size_t)(b * NN + i0 + w * 16 + quad * 4 + r) * INTER +
                         hh * HDIM + nt * 16 + l15;
            unsigned short uh = f2bf(v);
            ctxh[idx] = uh;
            ctxl[idx] = f2bf(v - bf2f(uh));
        }
}

// ---------------------------------------------------------------------------
extern "C" void kernel_launch(void* const* d_in, const int* in_sizes, int n_in,
                              void* d_out, int out_size, void* d_ws, size_t ws_size,
                              hipStream_t stream) {
    const float* features = (const float*)d_in[0];  // [B,N,DIM] fp32
    const int*   mask     = (const int*)d_in[1];    // [B,N,N]
    const float* W_qkv    = (const float*)d_in[2];  // [DIM, 3*INTER] fp32
    const float* W_out    = (const float*)d_in[3];  // [INTER, DIM] fp32
    float* out = (float*)d_out;                     // [B,N,DIM] fp32

    const int M = BB * NN;  // 4096
    char* ws = (char*)d_ws;
    unsigned short* qk2  = (unsigned short*)ws;                 // bf16 [4096][2048] 16.8 MB
    ws += (size_t)M * 2048 * 2;
    unsigned short* vtg  = (unsigned short*)ws;                 // bf16 [2][1024][2048] 8.4 MB
    ws += (size_t)BB * INTER * NN * 2;
    unsigned short* ctxh = (unsigned short*)ws;                 // bf16 [4096][1024] 8.4 MB
    ws += (size_t)M * INTER * 2;
    unsigned short* ctxl = (unsigned short*)ws;                 // bf16 [4096][1024] 8.4 MB
    ws += (size_t)M * INTER * 2;
    unsigned short* featb = (unsigned short*)ws;                // bf16 [4096][1024] 8.4 MB
    ws += (size_t)M * DIM * 2;
    unsigned short* wqt = (unsigned short*)ws;                  // bf16 [3072][1024] 6.3 MB
    // W_out^T hi/lo alias wqt's space (wqt dead after gemm_qkv; 4.2 MB <= 6.3 MB)
    unsigned short* woh = wqt;
    unsigned short* wol = wqt + (size_t)DIM * INTER;

    dim3 blk(256);

    conv_f32_bf16<<<dim3((M * DIM) / 1024), blk, 0, stream>>>(features, featb);
    transp_f32_bf16<<<dim3(QKVW / 64, DIM / 64), blk, 0, stream>>>(W_qkv, wqt, DIM, QKVW);

    // 1) qkv projection: q|k -> qk2, v -> vtg (transposed per head)
    gemm_qkv_mfma<<<dim3(QKVW / 128, M / 128), blk, 0, stream>>>(featb, wqt, qk2, vtg);

    // W_out^T split (after gemm_qkv: overwrites wqt space)
    transp_split_f32_bf16<<<dim3(DIM / 64, INTER / 64), blk, 0, stream>>>(
        W_out, woh, wol, INTER, DIM);

    // 2) segment-masked attention -> ctx (hi/lo bf16)
    attn_seg_mfma<<<dim3(NN / 64, NHEAD, BB), blk, 0, stream>>>(qk2, vtg, mask, ctxh, ctxl);

    // 3) out = ctx @ W_out, split-bf16 MFMA (3-term, ~fp32-exact)
    gemm_out_split<<<dim3(DIM / 64, M / 128), blk, 0, stream>>>(
        ctxh, ctxl, woh, wol, out);
}